// Round 7
// baseline (109.480 us; speedup 1.0000x reference)
//
#include <hip/hip_runtime.h>
#include <math.h>

#define N_INW   1024
#define N_DEPTH 8
#define N_GROW  512
#define N_BATCH 4096
#define COLSTR  9220            // bytes/col: 4608*2+4 -> 2305 dwords (odd: bank-spread)
#define LDS_B   (16 * COLSTR)   // 147520 B (< 160 KiB) -> 1 WG/CU
#define MAT_B   ((size_t)N_DEPTH * 64 * 1024)   // 512 KiB: 1024 B per (m, block)
#define ADR_OFF MAT_B                            // + 32 KiB u32 addr table

typedef __attribute__((ext_vector_type(4))) _Float16 h4;
typedef __attribute__((ext_vector_type(4))) float    f4;
typedef __attribute__((ext_vector_type(2))) float    F2;
typedef __attribute__((ext_vector_type(2))) unsigned u2;

#define PKU(x, y) __builtin_bit_cast(unsigned,                                 \
                      __builtin_amdgcn_cvt_pkrtz((x), (y)))

// ---- precompute: compose each half-module into a dense 16x16 f16 matrix ----
// Record (m, b): 1024 B. Lane l holds bytes l*16: [A_in frag 8 B | A_out frag 8 B]
// where frag element e (e=0..3) = M[row = l&15][k = (l>>4)*4 + e]  (HW-verified
// A-layout, rounds 5-6). Addr table: u32 byte-offset (row<<1) per (m, b, k).
__global__ void precompute_kernel(const float* __restrict__ angles,
                                  const int*   __restrict__ indices,
                                  char* __restrict__ ws) {
    int id = blockIdx.x * blockDim.x + threadIdx.x;
    if (id < 16384) {             // one thread = one column k of one 16x16 matrix
        int k = id & 15, b = (id >> 4) & 63, half = (id >> 10) & 1, m = id >> 11;
        float v[16];
#pragma unroll
        for (int i = 0; i < 16; ++i) v[i] = (i == k) ? 1.f : 0.f;
#pragma unroll
        for (int lp = 0; lp < 4; ++lp) {          // strides 1,2,4,8
            int s = 1 << lp;
            const float* ab = angles + m * 4096 + (half * 4 + lp) * 512 + b * 8;
#pragma unroll
            for (int p = 0; p < 8; ++p) {
                int qq = p >> lp, r = p & (s - 1);
                int lo = qq * 2 * s + r, hi = lo + s;
                float a = ab[p], c, sn;
                __sincosf(a, &sn, &c);
                float nl = c * v[lo] + sn * v[hi];
                float nh = c * v[hi] - sn * v[lo];
                v[lo] = nl; v[hi] = nh;
            }
        }
        char* rec = ws + ((size_t)(m * 64 + b) << 10);
#pragma unroll
        for (int row = 0; row < 16; ++row) {
            int lane = ((k >> 2) << 4) | row;
            *(unsigned short*)(rec + lane * 16 + half * 8 + (k & 3) * 2) =
                __builtin_bit_cast(unsigned short, (_Float16)v[row]);
        }
    }
    if (id < 8192) {              // [m][b*16+k] -> u32 LDS byte offset (2*row)
        ((unsigned*)(ws + ADR_OFF))[id] =
            (unsigned)(indices[(id >> 10) * N_INW + (id & 1023)] << 1);
    }
}

__device__ __forceinline__ float actf(float x) {
    return 0.5f * (x + __builtin_amdgcn_sqrtf(x * x + 1.0f));
}

#define DECLSET(P) h4 P##ai[4], P##ao[4]; uint4 P##ad[4];

// one 16-B mats load + one 16-B addr load per block per lane
#define LOADSET(P, M) do {                                                     \
    _Pragma("unroll")                                                          \
    for (int bb = 0; bb < 4; ++bb) {                                           \
        const int rb = (M) * 64 + wblk0 + bb;                                  \
        uint4 rc = *(const uint4*)(mats + ((size_t)rb << 10) + (lane << 4));   \
        u2 t0; t0.x = rc.x; t0.y = rc.y;                                       \
        u2 t1; t1.x = rc.z; t1.y = rc.w;                                       \
        P##ai[bb] = __builtin_bit_cast(h4, t0);                                \
        P##ao[bb] = __builtin_bit_cast(h4, t1);                                \
        P##ad[bb] = *(const uint4*)(adr + (size_t)rb * 64 + (q << 4));         \
    } } while (0)

// one module: prefetch next mats, issue bias loads + all gathers (latency
// overlapped), then per block: MFMA(in) -> act -> MFMA(out) -> scatter.
// One barrier per module.
#define PROC(P, NP, M, LAST) do {                                              \
  if (!(LAST)) LOADSET(NP, (M) + 1);                                           \
  f4 bi[4];                                                                    \
  _Pragma("unroll")                                                            \
  for (int bb = 0; bb < 4; ++bb)                                               \
    if (q < 2)                                                                 \
        bi[bb] = *(const f4*)(biases + (M) * N_GROW + (wblk0 + bb) * 8 +       \
                              ((q & 1) << 2));                                 \
  u2 bw[4];                                                                    \
  _Pragma("unroll")                                                            \
  for (int bb = 0; bb < 4; ++bb) {                                             \
    uint4 ad = P##ad[bb];                                                      \
    unsigned g0 = *(const unsigned short*)(L + cB + ad.x);                     \
    unsigned g1 = *(const unsigned short*)(L + cB + ad.y);                     \
    unsigned g2 = *(const unsigned short*)(L + cB + ad.z);                     \
    unsigned g3 = *(const unsigned short*)(L + cB + ad.w);                     \
    bw[bb].x = g0 | (g1 << 16); bw[bb].y = g2 | (g3 << 16);                    \
  }                                                                            \
  __builtin_amdgcn_s_setprio(1);                                               \
  _Pragma("unroll")                                                            \
  for (int bb = 0; bb < 4; ++bb) {                                             \
    const int blk = wblk0 + bb;                                                \
    f4 cin = (q < 2) ? bi[bb] : f4zero;                                        \
    f4 d = __builtin_amdgcn_mfma_f32_16x16x16f16(                              \
               P##ai[bb], __builtin_bit_cast(h4, bw[bb]), cin, 0, 0, 0);       \
    if (q < 2) {                                                               \
        d.x = actf(d.x); d.y = actf(d.y); d.z = actf(d.z); d.w = actf(d.w);    \
    }                                                                          \
    if (LAST) {                                                                \
        if (q < 2) {                                                           \
            float* op = out + (size_t)(blk * 8 + (q << 2)) * N_BATCH + cg + c; \
            op[0] = d.x; op[N_BATCH] = d.y;                                    \
            op[2 * N_BATCH] = d.z; op[3 * N_BATCH] = d.w;                      \
        }                                                                      \
    } else {                                                                   \
        unsigned p0 = PKU(d.x, d.y), p1 = PKU(d.z, d.w);                       \
        if (q < 2) {  /* activation rows into act region (canonical rows) */   \
            char* ap = L + cB +                                                \
                ((N_INW + (M) * N_GROW + blk * 8 + (q << 2)) << 1);            \
            *(unsigned*)ap = p0; *(unsigned*)(ap + 4) = p1;                    \
        }                                                                      \
        u2 bp; bp.x = p0; bp.y = p1;                                           \
        f4 d2 = __builtin_amdgcn_mfma_f32_16x16x16f16(                         \
                    P##ao[bb], __builtin_bit_cast(h4, bp), f4zero, 0, 0, 0);   \
        uint4 ad = P##ad[bb];                                                  \
        *(unsigned short*)(L + cB + ad.x) =                                    \
            __builtin_bit_cast(unsigned short, (_Float16)d2.x);                \
        *(unsigned short*)(L + cB + ad.y) =                                    \
            __builtin_bit_cast(unsigned short, (_Float16)d2.y);                \
        *(unsigned short*)(L + cB + ad.z) =                                    \
            __builtin_bit_cast(unsigned short, (_Float16)d2.z);                \
        *(unsigned short*)(L + cB + ad.w) =                                    \
            __builtin_bit_cast(unsigned short, (_Float16)d2.w);                \
    }                                                                          \
  }                                                                            \
  __builtin_amdgcn_s_setprio(0);                                               \
  if (!(LAST)) __syncthreads();                                                \
} while (0)

// 16 waves/WG (4 blocks each) -> 1 WG/CU (LDS-capped) but 4 waves/SIMD:
// double the latency-hiding of the 512-thread version at identical LDS
// layout and op counts. launch_bounds(1024,4) forces VGPR <= 128 so the
// whole WG is resident.
__global__ __launch_bounds__(1024, 4)
void butterfly_mfma_kernel(const float* __restrict__ input,
                           const float* __restrict__ scales,
                           const float* __restrict__ biases,
                           const char*  __restrict__ mats,
                           const char*  __restrict__ adr,
                           float* __restrict__ out) {
    extern __shared__ char L[];
    const int t = threadIdx.x, lane = t & 63, w = t >> 6;
    const int c = lane & 15, q = lane >> 4;      // col-in-tile, k-group
    const int cB = c * COLSTR;                   // column slab base (bytes)
    const int wblk0 = w * 4;                     // this wave's 4 blocks
    const int cg = blockIdx.x * 16;              // global column base
    const f4 f4zero = {0.f, 0.f, 0.f, 0.f};

    DECLSET(A) DECLSET(B)
    LOADSET(A, 0);

    // init rows 0..1023, vectorized: thread = (col-pair, 8-row group)
    {
        const int cp = (t & 7) << 1;             // columns cp, cp+1
        const int r0 = (t >> 3) << 3;            // rows r0..r0+7
#pragma unroll
        for (int i = 0; i < 8; i += 2) {
            int r = r0 + i;
            F2 w0 = *(const F2*)(input + (size_t)r * N_BATCH + cg + cp);
            F2 w1 = *(const F2*)(input + (size_t)(r + 1) * N_BATCH + cg + cp);
            F2 sc = *(const F2*)(scales + r);
            *(unsigned*)(L + cp * COLSTR + (r << 1))       = PKU(sc.x * w0.x, sc.y * w1.x);
            *(unsigned*)(L + (cp + 1) * COLSTR + (r << 1)) = PKU(sc.x * w0.y, sc.y * w1.y);
        }
    }
    __syncthreads();

#pragma unroll 1
    for (int tt = 0; tt < 3; ++tt) {
        PROC(A, B, 2 * tt, 0);
        PROC(B, A, 2 * tt + 1, 0);
    }
    PROC(A, B, 6, 0);
    PROC(B, B, 7, 1);   // module 7: activations -> global out (f32), no scatter
}

// ---------------- host ----------------
// The harness re-poisons d_ws unconditionally every iteration (round-4
// evidence), so workspace-based precompute is free. 512 KiB matrices +
// 32 KiB addr table.
extern "C" void kernel_launch(void* const* d_in, const int* in_sizes, int n_in,
                              void* d_out, int out_size, void* d_ws, size_t ws_size,
                              hipStream_t stream) {
    const float* input   = (const float*)d_in[0];
    const float* scales  = (const float*)d_in[1];
    const float* angles  = (const float*)d_in[2];
    const float* biases  = (const float*)d_in[3];
    const int*   indices = (const int*)d_in[4];
    float* out = (float*)d_out;

    precompute_kernel<<<64, 256, 0, stream>>>(angles, indices, (char*)d_ws);
    butterfly_mfma_kernel<<<256, 1024, LDS_B, stream>>>(
        input, scales, biases, (const char*)d_ws,
        (const char*)d_ws + ADR_OFF, out);
}

// Round 8
// 105.909 us; speedup vs baseline: 1.0337x; 1.0337x over previous
//
#include <hip/hip_runtime.h>
#include <math.h>

#define N_INW   1024
#define N_DEPTH 8
#define N_GROW  512
#define N_BATCH 4096
#define SLAB_B  19584                       // (4608 + 288 pad) dwords * 4 B
#define CS_BYTES  ((size_t)64 * 2048)       // 128 KiB fp16 cs table
#define ADR_OFF   CS_BYTES
#define ADR_BYTES ((size_t)8 * 1024 * 4)    // 32 KiB u32 addr table

typedef __attribute__((ext_vector_type(2))) float    F2;
typedef __attribute__((ext_vector_type(2))) _Float16 h2;
typedef __attribute__((ext_vector_type(2))) unsigned uu2;
typedef __attribute__((ext_vector_type(2))) int      i2;

// dword slab: row r -> half2 (2 cols) at byte (r + (r>>4))<<2
#define ADDR(r) ((((r) + ((r) >> 4))) << 2)

// ---- setup: fp16 cs table (layer g, blk: 8 cos @ g*2048+blk*32, 8 sin @ +16)
//      + u32 slab byte-offset table ----
__global__ void precompute_kernel(const float* __restrict__ angles,
                                  const int*   __restrict__ indices,
                                  char* __restrict__ ws) {
    int i = blockIdx.x * blockDim.x + threadIdx.x;
    if (i < 64 * 512) {
        int g = i >> 9, p = i & 511, blk = p >> 3, j = p & 7;
        float a = angles[i];
        _Float16* base = (_Float16*)(ws + g * 2048 + blk * 32);
        base[j]     = (_Float16)cosf(a);
        base[8 + j] = (_Float16)sinf(a);
    }
    if (i < 8192) {
        ((unsigned*)(ws + ADR_OFF))[i] = (unsigned)ADDR(indices[i]);
    }
}

#define LDH(A)    __builtin_bit_cast(h2, *(const unsigned*)(L + (A)))
#define STH(A, V) do { *(unsigned*)(L + (A)) =                                 \
                       __builtin_bit_cast(unsigned, (V)); } while (0)
#define PKU(x, y) __builtin_bit_cast(unsigned,                                 \
                      __builtin_amdgcn_cvt_pkrtz((x), (y)))
#define FENCE() __builtin_amdgcn_sched_barrier(0)

#define BCL(U) ({ h2 _t = __builtin_bit_cast(h2, (unsigned)(U));               \
                  h2 _r; _r.x = _t.x; _r.y = _t.x; _r; })
#define BCH(U) ({ h2 _t = __builtin_bit_cast(h2, (unsigned)(U));               \
                  h2 _r; _r.x = _t.y; _r.y = _t.y; _r; })

#define ROTPH(LO, HI, CC, SS) do { h2 _l = LO, _h = HI, _c = CC, _s = SS;      \
    LO = _c * _l + _s * _h; HI = _c * _h - _s * _l; } while (0)

// cross-half exchange: partner = x[lane ^ 32]
#if __has_builtin(__builtin_amdgcn_permlane32_swap)
#define XSWAP(X) ({ i2 _r = __builtin_amdgcn_permlane32_swap(                  \
                        (int)(X), (int)(X), false, false);                     \
                    (unsigned)(hb ? _r.x : _r.y); })
#else
#define XSWAP(X) ((unsigned)__builtin_amdgcn_ds_bpermute(pa, (int)(X)))
#endif

// stride-8 (cross-half) rotation on one dword: own' = c*own + s_eff*partner.
// s_eff pre-negated for hi-half lanes (nmask) so one formula serves both.
#define SW1(X, CW, SW_, SEL) do {                                              \
    unsigned _o = __builtin_bit_cast(unsigned, X);                             \
    h2 _pp = __builtin_bit_cast(h2, XSWAP(_o));                                \
    X = SEL(CW) * X + SEL(SW_) * _pp; } while (0)

// in-lane layers on this lane's 8 rows (4 pairs each; cs = uu2 = 4 f16)
#define HR1(C,S) do { ROTPH(x0,x1,BCL(C.x),BCL(S.x)); ROTPH(x2,x3,BCH(C.x),BCH(S.x)); \
                      ROTPH(x4,x5,BCL(C.y),BCL(S.y)); ROTPH(x6,x7,BCH(C.y),BCH(S.y)); } while (0)
#define HR2(C,S) do { ROTPH(x0,x2,BCL(C.x),BCL(S.x)); ROTPH(x1,x3,BCH(C.x),BCH(S.x)); \
                      ROTPH(x4,x6,BCL(C.y),BCL(S.y)); ROTPH(x5,x7,BCH(C.y),BCH(S.y)); } while (0)
#define HR4(C,S) do { ROTPH(x0,x4,BCL(C.x),BCL(S.x)); ROTPH(x1,x5,BCH(C.x),BCH(S.x)); \
                      ROTPH(x2,x6,BCL(C.y),BCL(S.y)); ROTPH(x3,x7,BCH(C.y),BCH(S.y)); } while (0)
#define HRS(C,S) do { SW1(x0,C.x,S.x,BCL); SW1(x1,C.x,S.x,BCH);                \
                      SW1(x2,C.y,S.y,BCL); SW1(x3,C.y,S.y,BCH);                \
                      SW1(x4,C.z,S.z,BCL); SW1(x5,C.z,S.z,BCH);                \
                      SW1(x6,C.w,S.w,BCL); SW1(x7,C.w,S.w,BCH); } while (0)

#define ACTH(X, BF) do {                                                       \
    float _lo = (float)(X).x + (BF), _hi = (float)(X).y + (BF);                \
    _lo = 0.5f * (_lo + __builtin_amdgcn_sqrtf(_lo * _lo + 1.0f));             \
    _hi = 0.5f * (_hi + __builtin_amdgcn_sqrtf(_hi * _hi + 1.0f));             \
    X = __builtin_bit_cast(h2, PKU(_lo, _hi)); } while (0)

// cs half-module: 3 in-lane layers (uu2 c,s = this half's 4 pairs) + 1 swap
// layer (uint4 c,s = all 8 pairs, s negated on hi half)
#define DECL_CS(P)  uu2 P##c0,P##s0,P##c1,P##s1,P##c2,P##s2; uint4 P##c3,P##s3;
#define DECL_SET(P) DECL_CS(P) uint4 P##g0, P##g1;

#define LOAD_CS4(P, M, LOFF) do {                                              \
    const char* _b = cs_tab + (size_t)(M)*16384 + (size_t)(LOFF)*2048 + (b<<5);\
    P##c0 = *(const uu2*)(_b +        (h<<3)); P##s0 = *(const uu2*)(_b +   16 + (h<<3)); \
    P##c1 = *(const uu2*)(_b + 2048 + (h<<3)); P##s1 = *(const uu2*)(_b + 2064 + (h<<3)); \
    P##c2 = *(const uu2*)(_b + 4096 + (h<<3)); P##s2 = *(const uu2*)(_b + 4112 + (h<<3)); \
    P##c3 = *(const uint4*)(_b + 6144);        P##s3 = *(const uint4*)(_b + 6160);        \
    P##s3.x ^= nmask; P##s3.y ^= nmask; P##s3.z ^= nmask; P##s3.w ^= nmask;    \
  } while (0)

#define LOAD_IN(P, M) do { LOAD_CS4(P, M, 0);                                  \
    const unsigned* _a = adr + (size_t)(M)*1024 + (b<<4) + (h<<3);             \
    P##g0 = *(const uint4*)_a; P##g1 = *(const uint4*)(_a + 4); } while (0)

// module M with IN-set P; prefetch module M+1 IN-set into N. OUT cs -> O.
// Two waves share the slab (disjoint block halves within a module); one
// barrier per module covers the scatter(M) -> gather(M+1) cross-wave edge.
#define PROC(P, N, M) do {                                                     \
  float4 bA = *(const float4*)(biases + (size_t)(M)*N_GROW + (b<<3));          \
  float4 bB = *(const float4*)(biases + (size_t)(M)*N_GROW + (b<<3) + 4);      \
  h2 x0=LDH(P##g0.x), x1=LDH(P##g0.y), x2=LDH(P##g0.z), x3=LDH(P##g0.w),       \
     x4=LDH(P##g1.x), x5=LDH(P##g1.y), x6=LDH(P##g1.z), x7=LDH(P##g1.w);       \
  LOAD_CS4(O, M, 4);                                                           \
  FENCE();                                                                     \
  HR1(P##c0,P##s0); HR2(P##c1,P##s1); HR4(P##c2,P##s2); HRS(P##c3,P##s3);      \
  if (h == 0) {                                                                \
    ACTH(x0,bA.x); ACTH(x1,bA.y); ACTH(x2,bA.z); ACTH(x3,bA.w);                \
    ACTH(x4,bB.x); ACTH(x5,bB.y); ACTH(x6,bB.z); ACTH(x7,bB.w);                \
    const int _ab = ADDR(N_INW + (M)*N_GROW + (b<<3));                         \
    STH(_ab+ 0,x0); STH(_ab+ 4,x1); STH(_ab+ 8,x2); STH(_ab+12,x3);            \
    STH(_ab+16,x4); STH(_ab+20,x5); STH(_ab+24,x6); STH(_ab+28,x7);            \
  }                                                                            \
  LOAD_IN(N, (M) + 1);                                                         \
  FENCE();                                                                     \
  HR1(Oc0,Os0); HR2(Oc1,Os1); HR4(Oc2,Os2); HRS(Oc3,Os3);                      \
  STH(P##g0.x,x0); STH(P##g0.y,x1); STH(P##g0.z,x2); STH(P##g0.w,x3);          \
  STH(P##g1.x,x4); STH(P##g1.y,x5); STH(P##g1.z,x6); STH(P##g1.w,x7);          \
  __syncthreads();                                                             \
} while (0)

// 256 thr = 4 waves; waves (0,1) share slab 0 (cols cg..cg+1), waves (2,3)
// share slab 1. Within a slab pair: wave owns 32 blocks; block's 16 rows
// split lanes (l, l+32) -> only the stride-8 layer crosses (permlane swap).
// LDS/WG = 39168 -> 4 WGs/CU = 16 waves/CU = 4 waves/SIMD (2x R0).
__global__ __launch_bounds__(256, 4)   // <=128 VGPR
void butterfly_fused_kernel(const float* __restrict__ input,
                            const float* __restrict__ scales,
                            const float* __restrict__ biases,
                            const char*  __restrict__ cs_tab,
                            const unsigned* __restrict__ adr,
                            float* __restrict__ out) {
    extern __shared__ char lds[];
    const int t  = threadIdx.x, l = t & 63, w = t >> 6;
    const int b  = ((w & 1) << 5) | (l & 31);   // butterfly block 0..63
    const int h  = l >> 5;                      // row-half (0: rows 0-7)
    const bool hb = (h != 0);
    const int pa = (l ^ 32) << 2; (void)pa;     // bpermute fallback addr
    const unsigned nmask = hb ? 0x80008000u : 0u;
    char* L = lds + (w >> 1) * SLAB_B;          // shared 2-col slab
    const int bid = blockIdx.x;
    // XCD swizzle: 1024 WGs, 4 cols each; slab -> col pair
    const int cg = ((((bid & 7) * 128) + (bid >> 3)) << 2) + ((w >> 1) << 1);

    DECL_SET(A) DECL_SET(B) DECL_CS(O)

    LOAD_IN(A, 0);

    // init rows 0..1023: 128 lanes (2 waves) x 8 rows, dword = 2 cols
    {
        const int r0 = ((((w & 1) << 6) | l) << 3);
        float4 s0 = *(const float4*)(scales + r0);
        float4 s1 = *(const float4*)(scales + r0 + 4);
#define INI(J, SC) do { F2 v = *(const F2*)(input + (size_t)(r0 + (J)) * N_BATCH + cg); \
        STH(ADDR(r0 + (J)), __builtin_bit_cast(h2, PKU((SC) * v.x, (SC) * v.y))); } while (0)
        INI(0, s0.x); INI(1, s0.y); INI(2, s0.z); INI(3, s0.w);
        INI(4, s1.x); INI(5, s1.y); INI(6, s1.z); INI(7, s1.w);
#undef INI
    }
    __syncthreads();

#pragma unroll 1
    for (int tt = 0; tt < 3; ++tt) {
        PROC(A, B, 2 * tt);
        PROC(B, A, 2 * tt + 1);
    }
    PROC(A, B, 6);                 // prefetches module 7 IN into B

    // epilogue: module 7 = IN rotations + act -> global out (OUT rots dead)
    {
        float4 bA = *(const float4*)(biases + (size_t)7 * N_GROW + (b << 3));
        float4 bB = *(const float4*)(biases + (size_t)7 * N_GROW + (b << 3) + 4);
        h2 x0=LDH(Bg0.x), x1=LDH(Bg0.y), x2=LDH(Bg0.z), x3=LDH(Bg0.w),
           x4=LDH(Bg1.x), x5=LDH(Bg1.y), x6=LDH(Bg1.z), x7=LDH(Bg1.w);
        FENCE();
        HR1(Bc0,Bs0); HR2(Bc1,Bs1); HR4(Bc2,Bs2); HRS(Bc3,Bs3);
        if (h == 0) {
            ACTH(x0,bA.x); ACTH(x1,bA.y); ACTH(x2,bA.z); ACTH(x3,bA.w);
            ACTH(x4,bB.x); ACTH(x5,bB.y); ACTH(x6,bB.z); ACTH(x7,bB.w);
#define OUTW(J, X) do { F2 _o; _o.x = (float)(X).x; _o.y = (float)(X).y;       \
            *(F2*)(out + (size_t)((b << 3) + (J)) * N_BATCH + cg) = _o; } while (0)
            OUTW(0,x0); OUTW(1,x1); OUTW(2,x2); OUTW(3,x3);
            OUTW(4,x4); OUTW(5,x5); OUTW(6,x6); OUTW(7,x7);
#undef OUTW
        }
    }
}

// ---------------- host ----------------
// d_ws is re-poisoned unconditionally every iteration (round-4 evidence),
// so table precompute is free. 128 KiB cs + 32 KiB addrs.
extern "C" void kernel_launch(void* const* d_in, const int* in_sizes, int n_in,
                              void* d_out, int out_size, void* d_ws, size_t ws_size,
                              hipStream_t stream) {
    const float* input   = (const float*)d_in[0];
    const float* scales  = (const float*)d_in[1];
    const float* angles  = (const float*)d_in[2];
    const float* biases  = (const float*)d_in[3];
    const int*   indices = (const int*)d_in[4];
    float* out = (float*)d_out;

    const size_t lds_bytes = (size_t)2 * SLAB_B;   // 39168 B
    precompute_kernel<<<128, 256, 0, stream>>>(angles, indices, (char*)d_ws);
    butterfly_fused_kernel<<<N_BATCH / 4, 256, lds_bytes, stream>>>(
        input, scales, biases, (const char*)d_ws,
        (const unsigned*)((const char*)d_ws + ADR_OFF), out);
}